// Round 1
// baseline (2072.200 us; speedup 1.0000x reference)
//
#include <hip/hip_runtime.h>
#include <hip/hip_bf16.h>

// Problem constants
#define T_STEPS 15
#define CIN     40
#define H_IN    160
#define W_IN    300
#define COUT    50
#define KH      4
#define KW      6
#define OH      157   // 160-4+1
#define OW      295   // 300-6+1
#define PH      52    // OH/3
#define PW      98    // OW/3
#define THRESH  15.0f

// Each thread: 10 co x 4 xx outputs at fixed (t, y).
// Work decomposition: widx -> (t, y, cog(5), xq(74))
__global__ __launch_bounds__(256) void conv_kernel(const float* __restrict__ x,
                                                   const float* __restrict__ w,
                                                   float* __restrict__ out) {
    const unsigned XQ = 74u;               // ceil(295/4)
    unsigned widx = blockIdx.x * 256u + threadIdx.x;
    unsigned xq  = widx % XQ;
    unsigned tmp = widx / XQ;
    unsigned cog = tmp % 5u;  tmp /= 5u;
    unsigned y   = tmp % 157u;
    unsigned t   = tmp / 157u;
    if (t >= (unsigned)T_STEPS) return;

    float acc[10][4];
    #pragma unroll
    for (int i = 0; i < 10; ++i)
        #pragma unroll
        for (int d = 0; d < 4; ++d) acc[i][d] = 0.f;

    const int xx0 = 4 * (int)xq;

    for (int ci = 0; ci < CIN; ++ci) {
        const float* xrow = x + (((t * CIN) + ci) * H_IN + y) * W_IN + xx0;
        const float* wrow = w + (cog * 10) * 960 + ci * 24;   // W[co][ci][ky][kx], 960 per co
        for (int ky = 0; ky < KH; ++ky) {
            const float* xr = xrow + ky * W_IN;
            float xv[9];
            float4 a = *reinterpret_cast<const float4*>(xr);      // xx0 is 16B aligned
            float4 b = *reinterpret_cast<const float4*>(xr + 4);
            xv[0]=a.x; xv[1]=a.y; xv[2]=a.z; xv[3]=a.w;
            xv[4]=b.x; xv[5]=b.y; xv[6]=b.z; xv[7]=b.w;
            xv[8] = (xx0 + 8 < W_IN) ? xr[8] : 0.f;               // only OOB at xq=73, masked output
            const float* wr = wrow + ky * 6;
            #pragma unroll
            for (int co = 0; co < 10; ++co) {
                float wv[6];
                #pragma unroll
                for (int kx = 0; kx < 6; ++kx) wv[kx] = wr[co * 960 + kx];
                #pragma unroll
                for (int kx = 0; kx < 6; ++kx)
                    #pragma unroll
                    for (int d = 0; d < 4; ++d)
                        acc[co][d] += wv[kx] * xv[kx + d];
            }
        }
    }

    // Store pots at d_out + 1 (element 0 is the decision scalar)
    #pragma unroll
    for (int co = 0; co < 10; ++co) {
        unsigned c = cog * 10u + (unsigned)co;
        float* o = out + 1 + (((t * COUT) + c) * OH + y) * OW + xx0;
        #pragma unroll
        for (int d = 0; d < 4; ++d)
            if (xx0 + d < OW) o[d] = acc[co][d];
    }
}

// Winner scan over pooled spikes of pots[t=14]: find min flat index (c,pi,pj)
// in row-major [50,52,98] whose 3x3 window has any pots >= 15.
__global__ __launch_bounds__(256) void scan_kernel(const float* __restrict__ out,
                                                   unsigned* __restrict__ ws) {
    unsigned idx = blockIdx.x * 256u + threadIdx.x;
    unsigned cand = ~0u;
    const unsigned TOT = COUT * PH * PW;
    if (idx < TOT) {
        unsigned c   = idx / (PH * PW);
        unsigned rem = idx % (PH * PW);
        unsigned pi  = rem / PW;
        unsigned pj  = rem % PW;
        const float* base = out + 1
            + ((((T_STEPS - 1) * COUT) + c) * OH + 3 * pi) * OW + 3 * pj;
        bool spike = false;
        #pragma unroll
        for (int r = 0; r < 3; ++r)
            #pragma unroll
            for (int s = 0; s < 3; ++s)
                spike = spike || (base[r * OW + s] >= THRESH);
        if (spike) cand = idx;
    }
    // wave-level min reduction, one atomic per wave
    #pragma unroll
    for (int off = 32; off > 0; off >>= 1) {
        unsigned o = __shfl_down(cand, off, 64);
        cand = cand < o ? cand : o;
    }
    if ((threadIdx.x & 63u) == 0u && cand != ~0u) atomicMin(ws, cand);
}

__global__ void init_kernel(unsigned* ws) { ws[0] = ~0u; }

__global__ void fin_kernel(const unsigned* __restrict__ ws, float* __restrict__ out) {
    unsigned m = ws[0];
    int dec = (m == ~0u) ? -1 : (int)((m / (PH * PW)) / 20u);
    out[0] = (float)dec;
}

extern "C" void kernel_launch(void* const* d_in, const int* in_sizes, int n_in,
                              void* d_out, int out_size, void* d_ws, size_t ws_size,
                              hipStream_t stream) {
    const float* x = (const float*)d_in[0];
    const float* w = (const float*)d_in[1];
    float* out     = (float*)d_out;
    unsigned* ws   = (unsigned*)d_ws;

    hipLaunchKernelGGL(init_kernel, dim3(1), dim3(1), 0, stream, ws);

    unsigned work   = 15u * 157u * 5u * 74u;   // (t, y, cog, xq)
    unsigned blocks = (work + 255u) / 256u;
    hipLaunchKernelGGL(conv_kernel, dim3(blocks), dim3(256), 0, stream, x, w, out);

    unsigned tot = COUT * PH * PW;
    hipLaunchKernelGGL(scan_kernel, dim3((tot + 255u) / 256u), dim3(256), 0, stream, out, ws);

    hipLaunchKernelGGL(fin_kernel, dim3(1), dim3(1), 0, stream, ws, out);
}

// Round 2
// 556.452 us; speedup vs baseline: 3.7240x; 3.7240x over previous
//
#include <hip/hip_runtime.h>
#include <hip/hip_bf16.h>

// Problem constants
#define T_STEPS 15
#define CIN     40
#define H_IN    160
#define W_IN    300
#define COUT    50
#define KH      4
#define KW      6
#define OH      157   // 160-4+1
#define OW      295   // 300-6+1
#define PH      52    // OH/3
#define PW      98    // OW/3
#define THRESH  15.0f

// Implicit-GEMM geometry
#define K2      160   // k2 = ci*4 + ky
#define COP     64    // couts padded to 64 (4 m-tiles of 16)
#define CT      64    // x-columns per block tile (4 n-tiles of 16)
#define XROWS   70    // CT + KW
#define ROWB    320   // bytes per XT row (160 bf16)

typedef __attribute__((ext_vector_type(8))) short  short8v;
typedef __attribute__((ext_vector_type(4))) float  float4v;

__device__ __forceinline__ unsigned short f2bf(float f) {
    unsigned u = __float_as_uint(f);
    u += 0x7FFFu + ((u >> 16) & 1u);          // round-to-nearest-even
    return (unsigned short)(u >> 16);
}

// XT[c][k2] bf16 with XOR swizzle: 16-lane b128 reads at row stride 320B
// would alias 2 banks; ^((c&7)<<4) spreads each 8-row group across 8
// distinct 16B blocks -> 2-way (free). Swizzle stays inside the 320B row.
__device__ __forceinline__ unsigned xt_addr(unsigned c, unsigned k2) {
    unsigned a = c * (unsigned)ROWB + k2 * 2u;
    return a ^ ((c & 7u) << 4);
}

// W2[kx][co(64)][k2(160)] bf16, zero-padded co>=50
__global__ __launch_bounds__(256) void w2_kernel(const float* __restrict__ w,
                                                 unsigned short* __restrict__ w2) {
    unsigned idx = blockIdx.x * 256u + threadIdx.x;
    if (idx >= 6u * COP * K2) return;
    unsigned k2 = idx % K2;
    unsigned tmp = idx / K2;
    unsigned co = tmp % COP;
    unsigned kx = tmp / COP;
    float v = 0.f;
    if (co < COUT) {
        unsigned ci = k2 >> 2, ky = k2 & 3u;
        v = w[co * 960u + ci * 24u + ky * 6u + kx];   // W[co][ci][ky][kx]
    }
    w2[idx] = f2bf(v);
}

// One block: (t, y, xtile). 4 waves; wave = m-tile (16 couts), each wave
// computes 16co x 64x. K = 960 done as 6 shifted GEMMs (kx) of K2=160.
__global__ __launch_bounds__(256) void conv_mfma(const float* __restrict__ x,
                                                 const unsigned short* __restrict__ w2,
                                                 float* __restrict__ out) {
    __shared__ char lds[XROWS * ROWB];   // 22400 B
    const unsigned xt = blockIdx.x, y = blockIdx.y, t = blockIdx.z;
    const unsigned tid  = threadIdx.x;
    const unsigned wave = tid >> 6, lane = tid & 63u;
    const unsigned xbase = xt * CT;

    // ---- stage XT[c][k2] = bf16(x[t][ci][y+ky][xbase+c]) ----
    for (unsigned k2 = wave; k2 < K2; k2 += 4u) {
        unsigned ci = k2 >> 2, ky = k2 & 3u;
        const float* row = x + (((t * CIN) + ci) * H_IN + (y + ky)) * W_IN + xbase;
        float v = (xbase + lane < W_IN) ? row[lane] : 0.f;
        *(unsigned short*)(lds + xt_addr(lane, k2)) = f2bf(v);
        if (lane < (XROWS - CT)) {
            unsigned c2 = CT + lane;
            float v2 = (xbase + c2 < W_IN) ? row[c2] : 0.f;
            *(unsigned short*)(lds + xt_addr(c2, k2)) = f2bf(v2);
        }
    }
    __syncthreads();

    const unsigned m0 = wave * 16u;
    const unsigned lo = lane & 15u, hi = lane >> 4;

    float4v acc[4];
    #pragma unroll
    for (int nt = 0; nt < 4; ++nt) acc[nt] = (float4v){0.f, 0.f, 0.f, 0.f};

    #pragma unroll
    for (unsigned kx = 0; kx < 6; ++kx) {
        // A-frags: 5 k-steps, 16B contiguous loads from W2 (L1/L2-hot)
        short8v a[5];
        const unsigned short* wbase = w2 + (kx * COP + m0 + lo) * K2 + 8u * hi;
        #pragma unroll
        for (int ks = 0; ks < 5; ++ks)
            a[ks] = *reinterpret_cast<const short8v*>(wbase + ks * 32);
        #pragma unroll
        for (int nt = 0; nt < 4; ++nt) {
            unsigned c = nt * 16u + lo + kx;        // <= 68 < XROWS
            #pragma unroll
            for (int ks = 0; ks < 5; ++ks) {
                short8v b = *reinterpret_cast<const short8v*>(
                    lds + xt_addr(c, (unsigned)ks * 32u + 8u * hi));
                acc[nt] = __builtin_amdgcn_mfma_f32_16x16x32_bf16(a[ks], b, acc[nt], 0, 0, 0);
            }
        }
    }

    // ---- epilogue: D[m][n] lane map: co = m0+4*hi+r, x = n0+lo ----
    #pragma unroll
    for (int nt = 0; nt < 4; ++nt) {
        unsigned xcol = xbase + nt * 16u + lo;
        if (xcol >= OW) continue;
        #pragma unroll
        for (int r = 0; r < 4; ++r) {
            unsigned co = m0 + 4u * hi + (unsigned)r;
            if (co < COUT)
                out[1 + ((((t * COUT) + co) * OH + y) * OW + xcol)] = acc[nt][r];
        }
    }
}

// Winner scan over pooled spikes of pots[t=14]: min flat index (c,pi,pj)
// in row-major [50,52,98] whose 3x3 window has any pots >= 15.
__global__ __launch_bounds__(256) void scan_kernel(const float* __restrict__ out,
                                                   unsigned* __restrict__ ws) {
    unsigned idx = blockIdx.x * 256u + threadIdx.x;
    unsigned cand = ~0u;
    const unsigned TOT = COUT * PH * PW;
    if (idx < TOT) {
        unsigned c   = idx / (PH * PW);
        unsigned rem = idx % (PH * PW);
        unsigned pi  = rem / PW;
        unsigned pj  = rem % PW;
        const float* base = out + 1
            + ((((T_STEPS - 1) * COUT) + c) * OH + 3 * pi) * OW + 3 * pj;
        bool spike = false;
        #pragma unroll
        for (int r = 0; r < 3; ++r)
            #pragma unroll
            for (int s = 0; s < 3; ++s)
                spike = spike || (base[r * OW + s] >= THRESH);
        if (spike) cand = idx;
    }
    #pragma unroll
    for (int off = 32; off > 0; off >>= 1) {
        unsigned o = __shfl_down(cand, off, 64);
        cand = cand < o ? cand : o;
    }
    if ((threadIdx.x & 63u) == 0u && cand != ~0u) atomicMin(ws, cand);
}

__global__ void init_kernel(unsigned* ws) { ws[0] = ~0u; }

__global__ void fin_kernel(const unsigned* __restrict__ ws, float* __restrict__ out) {
    unsigned m = ws[0];
    int dec = (m == ~0u) ? -1 : (int)((m / (PH * PW)) / 20u);
    out[0] = (float)dec;
}

extern "C" void kernel_launch(void* const* d_in, const int* in_sizes, int n_in,
                              void* d_out, int out_size, void* d_ws, size_t ws_size,
                              hipStream_t stream) {
    const float* x = (const float*)d_in[0];
    const float* w = (const float*)d_in[1];
    float* out     = (float*)d_out;
    unsigned* wsu  = (unsigned*)d_ws;
    unsigned short* w2 = (unsigned short*)((char*)d_ws + 256);  // 123 KB

    hipLaunchKernelGGL(init_kernel, dim3(1), dim3(1), 0, stream, wsu);

    hipLaunchKernelGGL(w2_kernel, dim3((6u * COP * K2 + 255u) / 256u), dim3(256),
                       0, stream, w, w2);

    hipLaunchKernelGGL(conv_mfma, dim3(5, 157, 15), dim3(256), 0, stream,
                       x, w2, out);

    unsigned tot = COUT * PH * PW;
    hipLaunchKernelGGL(scan_kernel, dim3((tot + 255u) / 256u), dim3(256), 0, stream,
                       out, wsu);

    hipLaunchKernelGGL(fin_kernel, dim3(1), dim3(1), 0, stream, wsu, out);
}